// Round 1
// 119.928 us; speedup vs baseline: 1.0539x; 1.0539x over previous
//
#include <hip/hip_runtime.h>
#include <hip/hip_bf16.h>

// MultiHeadAttentionLegacy: B=2, S=2048, E=768, H=12, HD=64, G=B*H=24
// Inputs fp32, output fp32; internal bf16 MFMA pipeline.
// Legacy reshape = pure flat re-chunk: [4096][768] buffer == 24 slabs [2048][64].
// Softmax denominator over FULL row; tril mask applied AFTER softmax.
// Q projection pre-scaled by log2(e)/sqrt(64) so attention uses exp2 directly.
//
// R1: pre-convert q/k/v fp32->bf16 (cvt_qkv) so the QKV GEMM uses the
// fire-and-forget global_load_lds path for A as well as B. The old MODE 0
// A-path (load fp32 -> vmcnt wait -> cvt -> ds_write) exposed full memory
// latency every k-step and moved 2x the bytes.

typedef __bf16 bf16;
typedef __attribute__((ext_vector_type(4))) __bf16 bf16x4;
typedef __attribute__((ext_vector_type(8))) __bf16 bf16x8;
typedef __attribute__((ext_vector_type(4))) float f32x4;
typedef __attribute__((ext_vector_type(16))) float f32x16;
typedef __attribute__((ext_vector_type(4))) unsigned int uint4v;

#define MFMA16(a,b,c) __builtin_amdgcn_mfma_f32_16x16x32_bf16((a),(b),(c),0,0,0)
#define MFMA32(a,b,c) __builtin_amdgcn_mfma_f32_32x32x16_bf16((a),(b),(c),0,0,0)

typedef const __attribute__((address_space(1))) unsigned int GU32;
typedef __attribute__((address_space(3))) unsigned int LU32;

__device__ __forceinline__ void gll16(const void* gsrc, void* ldst) {
    __builtin_amdgcn_global_load_lds((GU32*)gsrc, (LU32*)ldst, 16, 0, 0);
}

__device__ __forceinline__ unsigned pk_bf16(float lo, float hi) {
    unsigned r;
    asm("v_cvt_pk_bf16_f32 %0, %1, %2" : "=v"(r) : "v"(lo), "v"(hi));
    return r;
}

// v_permlane32_swap_b32: a.hi32lanes <-> b.lo32lanes
__device__ __forceinline__ void plane32swap(unsigned &a, unsigned &b) {
    asm("v_permlane32_swap_b32 %0, %1" : "+v"(a), "+v"(b));
}

__device__ __forceinline__ bf16x8 frag_words(unsigned w0, unsigned w1, unsigned w2, unsigned w3) {
    union { unsigned u[4]; bf16x8 v; } f;
    f.u[0] = w0; f.u[1] = w1; f.u[2] = w2; f.u[3] = w3;
    return f.v;
}

// ------- fp32 -> bf16 streaming convert for q/k/v activations -------
// grid (1536, 3): y selects matrix, each block converts 2048 elems.
__global__ __launch_bounds__(256) void cvt_qkv(
    const float* __restrict__ q, const float* __restrict__ k, const float* __restrict__ v,
    bf16* __restrict__ Qb, bf16* __restrict__ Kb, bf16* __restrict__ Vb)
{
    const float* src = blockIdx.y == 0 ? q : blockIdx.y == 1 ? k : v;
    bf16* dst = blockIdx.y == 0 ? Qb : blockIdx.y == 1 ? Kb : Vb;
    const size_t base = (size_t)blockIdx.x * 2048 + (size_t)threadIdx.x * 8;
    f32x4 lo = *(const f32x4*)&src[base];
    f32x4 hi = *(const f32x4*)&src[base + 4];
    bf16x8 o;
    for (int j = 0; j < 4; ++j) { o[j] = (bf16)lo[j]; o[4 + j] = (bf16)hi[j]; }
    *(bf16x8*)&dst[base] = o;
}

// ------- weight transpose + cvt: out_bf16[n*768+k] = (bf16)in_f32[k*768+n] -------
struct TArg { const float* in; bf16* out; };

__global__ __launch_bounds__(256) void transpose_w(TArg a0, TArg a1, TArg a2, TArg a3) {
    TArg ta = blockIdx.z == 0 ? a0 : blockIdx.z == 1 ? a1 : blockIdx.z == 2 ? a2 : a3;
    __shared__ bf16 tile[64][72];
    const int bx = blockIdx.x % 12, by = blockIdx.x / 12;
    const int k0 = by * 64, n0 = bx * 64;
    const int tid = threadIdx.x;
    for (int q = 0; q < 2; ++q) {
        int idx = q * 256 + tid;
        int i = idx >> 3, j0 = (idx & 7) * 8;
        const float* src = &ta.in[(size_t)(k0 + i) * 768 + n0 + j0];
        f32x4 lo = *(const f32x4*)&src[0];
        f32x4 hi = *(const f32x4*)&src[4];
        bf16x8 v;
        for (int j = 0; j < 4; ++j) { v[j] = (bf16)lo[j]; v[4 + j] = (bf16)hi[j]; }
        *(bf16x8*)&tile[i][j0] = v;
    }
    __syncthreads();
    for (int q = 0; q < 2; ++q) {
        int idx = q * 256 + tid;
        int n = idx >> 3, j0 = (idx & 7) * 8;
        bf16x8 v;
        for (int jj = 0; jj < 8; ++jj) v[jj] = tile[j0 + jj][n];
        *(bf16x8*)&ta.out[(size_t)(n0 + n) * 768 + k0 + j0] = v;
    }
}

// ------- V slab transpose: Vt[g][d][k] = Vp[g*131072 + k*64 + d] -------
__global__ __launch_bounds__(256) void vtrans(const bf16* __restrict__ Vp, bf16* __restrict__ Vt) {
    __shared__ bf16 tile[64][72];
    const int g = blockIdx.y;
    const int k0 = blockIdx.x * 64;
    const bf16* src = Vp + (size_t)g * 131072;
    bf16* dst = Vt + (size_t)g * 131072;
    const int tid = threadIdx.x;
    for (int q = 0; q < 2; ++q) {
        int idx = q * 256 + tid;
        int r = idx >> 3, c = (idx & 7) * 8;
        *(uint4v*)&tile[r][c] = *(const uint4v*)&src[(size_t)(k0 + r) * 64 + c];
    }
    __syncthreads();
    for (int q = 0; q < 2; ++q) {
        int idx = q * 256 + tid;
        int d = idx >> 3, c = (idx & 7) * 8;
        bf16x8 v;
        for (int j = 0; j < 8; ++j) v[j] = tile[c + j][d];
        *(bf16x8*)&dst[(size_t)d * 2048 + k0 + c] = v;
    }
}

// --- GEMM: C[4096x768] = (A @ Bt^T + bias) * scale.  A is bf16 always.
//     MODE 0: C bf16 (proj);  MODE 1: C fp32 (out) ---
struct GArg { const bf16* A; const bf16* Bt; const float* bias; void* C; float scale; };

template<int MODE>
__global__ __launch_bounds__(256) void gemm_bt_bias(GArg g0, GArg g1, GArg g2) {
    GArg ga = blockIdx.z == 0 ? g0 : blockIdx.z == 1 ? g1 : g2;
    const int K = 768, N = 768;
    __shared__ bf16 As[2][128][64];
    __shared__ bf16 Bs[2][128][64];
    const int tid = threadIdx.x;
    const int lane = tid & 63, wave = tid >> 6;
    const int l15 = lane & 15, lg = lane >> 4;
    const int r0 = blockIdx.y * 128, c0 = blockIdx.x * 128;
    const int wr = (wave >> 1) * 64, wc = (wave & 1) * 64;
    f32x4 acc[4][4] = {};

    const int grow = wave * 8 + (lane >> 3);
    const int gcol = 8 * ((lane & 7) ^ (lane >> 3));

    auto stage = [&](int kt, int buf) {
        for (int i = 0; i < 4; ++i)
            gll16(&ga.A[(size_t)(r0 + i * 32 + grow) * K + kt + gcol], &As[buf][i * 32 + wave * 8][0]);
        for (int i = 0; i < 4; ++i)
            gll16(&ga.Bt[(size_t)(c0 + i * 32 + grow) * K + kt + gcol], &Bs[buf][i * 32 + wave * 8][0]);
    };

    stage(0, 0);
    __syncthreads();

    for (int c = 0; c < 12; ++c) {
        const int buf = c & 1;
        if (c < 11) stage((c + 1) * 64, buf ^ 1);   // fire-and-forget, drained at barrier
        for (int kk = 0; kk < 2; ++kk) {
            bf16x8 af[4], bfr[4];
            for (int i = 0; i < 4; ++i) {
                int row = wr + i * 16 + l15;
                af[i] = *(const bf16x8*)&As[buf][row][(kk * 32 + lg * 8) ^ ((row & 7) * 8)];
            }
            for (int j = 0; j < 4; ++j) {
                int row = wc + j * 16 + l15;
                bfr[j] = *(const bf16x8*)&Bs[buf][row][(kk * 32 + lg * 8) ^ ((row & 7) * 8)];
            }
            __builtin_amdgcn_s_setprio(1);
            for (int i = 0; i < 4; ++i)
                for (int j = 0; j < 4; ++j)
                    acc[i][j] = MFMA16(af[i], bfr[j], acc[i][j]);
            __builtin_amdgcn_s_setprio(0);
        }
        __syncthreads();
    }
    for (int j = 0; j < 4; ++j) {
        int col = c0 + wc + j * 16 + l15;
        float bv = ga.bias[col];
        for (int i = 0; i < 4; ++i) {
            int row = r0 + wr + i * 16 + lg * 4;
            for (int r = 0; r < 4; ++r) {
                float val = (acc[i][j][r] + bv) * ga.scale;
                if constexpr (MODE == 0)
                    ((bf16*)ga.C)[(size_t)(row + r) * N + col] = (bf16)val;
                else
                    ((float*)ga.C)[(size_t)(row + r) * N + col] = val;
            }
        }
    }
}

// ------- attention v5: 32x32 MFMA, in-register P, k-split wave pairs, 768 blocks -------
// Block = 4 waves over 64 q-rows. Wave (wq=w>>1, p=w&1): q rows t0+wq*32..+31,
// k-half p of each 64-chunk. Swapped QK: S-regs q=lane&31, k=(r&3)+8*(r>>2)+4*hi.
// Cross-pair O/denom reduce via LDS overlay at the end.
__global__ __launch_bounds__(256) void attn_kernel(
    const bf16* __restrict__ Qp, const bf16* __restrict__ Kp,
    const bf16* __restrict__ Vtg, bf16* __restrict__ Ob)
{
    // XCD swizzle: 768 blocks = 8 XCDs x 96; 96 = 3 whole groups -> L2-local K/V
    const int bid = blockIdx.x;
    const int wg = (bid & 7) * 96 + (bid >> 3);
    const int g = wg >> 5, bx = wg & 31;
    const int t0 = bx * 64;
    const int tid = threadIdx.x, lane = tid & 63, w = tid >> 6;
    const int wq = w >> 1, p = w & 1;
    const int l31 = lane & 31, hi = lane >> 5;

    __shared__ __align__(16) char smem[32768];
    bf16 (*Ks)[64][64] = (bf16(*)[64][64])smem;             // [2][k][d], d-swizzled
    bf16 (*Vs)[64][64] = (bf16(*)[64][64])(smem + 16384);   // [2][d][k], k-swizzled

    const bf16* Qg = Qp + (size_t)g * 131072;
    const bf16* Kg = Kp + (size_t)g * 131072;
    const bf16* Vg = Vtg + (size_t)g * 131072;   // [64][2048]
    bf16* Og = Ob + (size_t)g * 131072;

    // Q B-frags in registers: col=q=l31, k-dim d = m*16 + hi*8 + j
    const int qrow = t0 + wq * 32 + l31;
    bf16x8 qB[4];
    for (int m = 0; m < 4; ++m)
        qB[m] = *(const bf16x8*)&Qg[(size_t)qrow * 64 + m * 16 + hi * 8];

    // staging: wave stages 16 rows (2 gll of 8 rows), pre-swizzled source col
    const int srow = w * 16 + (lane >> 3);
    const int scol = 8 * ((lane & 7) ^ (lane >> 3));
    auto stageK = [&](int ch, int b2) {
        const bf16* src = &Kg[(size_t)(ch * 64 + srow) * 64 + scol];
        gll16(src, &Ks[b2][w * 16][0]);
        gll16(src + 8 * 64, &Ks[b2][w * 16 + 8][0]);
    };
    auto stageV = [&](int ch, int b2) {
        const bf16* src = &Vg[(size_t)srow * 2048 + ch * 64 + scol];
        gll16(src, &Vs[b2][w * 16][0]);
        gll16(src + 8 * 2048, &Vs[b2][w * 16 + 8][0]);
    };

    stageK(0, 0);
    stageV(0, 0);

    f32x16 oacc0 = {}, oacc1 = {};
    float dsum = 0.f;
    const int qmin = t0 + wq * 32, qmax = qmin + 31;   // wave's q range
    const int kofs = p * 32;                            // wave's k-half offset
    const int swz = (l31 & 7) * 8;

    for (int c = 0; c < 32; ++c) {
        const int b = c & 1;
        asm volatile("s_waitcnt vmcnt(0)" ::: "memory");
        __builtin_amdgcn_s_barrier();
        __builtin_amdgcn_sched_barrier(0);
        if (c < 31) {
            stageK(c + 1, b ^ 1);
            if (c + 1 <= bx) stageV(c + 1, b ^ 1);
        }
        __builtin_amdgcn_sched_barrier(0);

        const int kc = c * 64;
        const bool activ = (kc + kofs <= qmax);         // wave-uniform
        const bool fullc = (kc + kofs + 31 <= qmin);    // wave-uniform

        // ---- QK^T: A = K rows (wave's 32-k half), B = Q regs
        f32x16 s = {};
        __builtin_amdgcn_s_setprio(1);
        for (int m = 0; m < 4; ++m) {
            bf16x8 kf = *(const bf16x8*)&Ks[b][kofs + l31][(m * 16 + hi * 8) ^ swz];
            s = MFMA32(kf, qB[m], s);
        }
        __builtin_amdgcn_s_setprio(0);

        // ---- exp2 (Q pre-scaled by log2e/8) + denominator (UNmasked)
        float e[16];
        for (int r = 0; r < 16; ++r) e[r] = __builtin_exp2f(s[r]);
        float acc = 0.f;
        for (int r = 0; r < 16; ++r) acc += e[r];
        dsum += acc;

        if (activ) {
            if (!fullc) {   // diagonal: tril AFTER softmax
                for (int r = 0; r < 16; ++r) {
                    int kg = kc + kofs + (r & 3) + 8 * (r >> 2) + 4 * hi;
                    if (kg > qrow) e[r] = 0.f;
                }
            }
            // ---- pack P to bf16 + permlane32_swap -> 2 PV A-frags, no LDS
            bf16x8 pf[2];
            {
                unsigned a0 = pk_bf16(e[0], e[1]), a1 = pk_bf16(e[2], e[3]);
                unsigned b0 = pk_bf16(e[4], e[5]), b1 = pk_bf16(e[6], e[7]);
                plane32swap(a0, b0); plane32swap(a1, b1);
                pf[0] = frag_words(a0, a1, b0, b1);
                a0 = pk_bf16(e[8], e[9]);   a1 = pk_bf16(e[10], e[11]);
                b0 = pk_bf16(e[12], e[13]); b1 = pk_bf16(e[14], e[15]);
                plane32swap(a0, b0); plane32swap(a1, b1);
                pf[1] = frag_words(a0, a1, b0, b1);
            }
            // ---- PV: A = P frags, B = V^T tile (col d, row k)
            __builtin_amdgcn_s_setprio(1);
            for (int kt = 0; kt < 2; ++kt) {
                const int col = (kofs + kt * 16 + hi * 8) ^ swz;
                bf16x8 v0 = *(const bf16x8*)&Vs[b][l31][col];
                bf16x8 v1 = *(const bf16x8*)&Vs[b][32 + l31][col];
                oacc0 = MFMA32(pf[kt], v0, oacc0);
                oacc1 = MFMA32(pf[kt], v1, oacc1);
            }
            __builtin_amdgcn_s_setprio(0);
        }
    }

    // ---- wave-internal k reduce: lane & lane^32 hold complementary k for q=l31
    dsum += __shfl_xor(dsum, 32);

    // ---- cross-pair reduce via LDS overlay (Ks/Vs regions dead after loop)
    __syncthreads();
    float* Ored = (float*)smem;                 // [pair][q 0-31][d 0-63] = 2 x 8KB
    float* dred = (float*)(smem + 16384);       // [wave][q 0-31] = 512 B
    if (l31 == lane) dred[w * 32 + l31] = dsum; // lanes 0-31 only
    if (p == 1) {
        float* Op = Ored + wq * 2048;
        for (int r = 0; r < 16; ++r) {
            const int qoff = (r & 3) + 8 * (r >> 2) + 4 * hi;
            Op[qoff * 64 + l31]      = oacc0[r];
            Op[qoff * 64 + 32 + l31] = oacc1[r];
        }
    }
    __syncthreads();
    if (p == 0) {
        const float dtot = dsum + dred[(w + 1) * 32 + l31];
        const float rall = 1.0f / dtot;          // valid for q=l31 at every lane
        const float* Op = Ored + wq * 2048;
        for (int r = 0; r < 16; ++r) {
            const int qoff = (r & 3) + 8 * (r >> 2) + 4 * hi;
            const float inv = __shfl(rall, qoff);
            const size_t row = (size_t)(t0 + wq * 32 + qoff) * 64;
            Og[row + l31]      = (bf16)((oacc0[r] + Op[qoff * 64 + l31])      * inv);
            Og[row + 32 + l31] = (bf16)((oacc1[r] + Op[qoff * 64 + 32 + l31]) * inv);
        }
    }
}

// ---------------- host ----------------
extern "C" void kernel_launch(void* const* d_in, const int* in_sizes, int n_in,
                              void* d_out, int out_size, void* d_ws, size_t ws_size,
                              hipStream_t stream) {
    const float* query = (const float*)d_in[0];
    const float* key_  = (const float*)d_in[1];
    const float* value = (const float*)d_in[2];
    const float* Wq = (const float*)d_in[3];
    const float* bq = (const float*)d_in[4];
    const float* Wk = (const float*)d_in[5];
    const float* bk = (const float*)d_in[6];
    const float* Wv = (const float*)d_in[7];
    const float* bv = (const float*)d_in[8];
    const float* Wo = (const float*)d_in[9];
    const float* bo = (const float*)d_in[10];
    float* out = (float*)d_out;

    const size_t MN = (size_t)4096 * 768;
    const size_t WW = (size_t)768 * 768;
    bf16* Qp  = (bf16*)d_ws;
    bf16* Kp  = Qp + MN;
    bf16* Vp  = Kp + MN;
    bf16* Obf = Vp + MN;
    bf16* Vtg = Obf + MN;
    bf16* WtQ = Vtg + MN;
    bf16* WtK = WtQ + WW;
    bf16* WtV = WtK + WW;
    bf16* WtO = WtV + WW;
    bf16* Vb  = WtO + WW;    // +1 MN slab
    // bf16 activation inputs: Qb/Kb alias slabs that are only written later
    // (Obf by attn, Vtg by vtrans) — both dead until after gemm<0> consumes them.
    bf16* Qb  = Obf;
    bf16* Kb  = Vtg;

    cvt_qkv<<<dim3(1536, 3), 256, 0, stream>>>(query, key_, value, Qb, Kb, Vb);

    transpose_w<<<dim3(144, 1, 4), 256, 0, stream>>>(
        TArg{Wq, WtQ}, TArg{Wk, WtK}, TArg{Wv, WtV}, TArg{Wo, WtO});

    // fold log2(e)/sqrt(HD) into Q so attention uses native exp2
    gemm_bt_bias<0><<<dim3(6, 32, 3), 256, 0, stream>>>(
        GArg{Qb, WtQ, bq, Qp, 0.18033688f},
        GArg{Kb, WtK, bk, Kp, 1.0f},
        GArg{Vb, WtV, bv, Vp, 1.0f});

    vtrans<<<dim3(32, 24), 256, 0, stream>>>(Vp, Vtg);

    attn_kernel<<<dim3(768), 256, 0, stream>>>(Qp, Kp, Vtg, Obf);

    gemm_bt_bias<1><<<dim3(6, 32, 1), 256, 0, stream>>>(
        GArg{Obf, WtO, bo, out, 1.0f},
        GArg{Obf, WtO, bo, out, 1.0f},
        GArg{Obf, WtO, bo, out, 1.0f});
}